// Round 5
// baseline (168.359 us; speedup 1.0000x reference)
//
#include <hip/hip_runtime.h>

// MSDeformAttn sampling-weight scatter (RankDetr), bug-compatible with the
// reference's axis-mislabeled reshape: output column q' = m/48, m=(l*8+h)*300+q.
//
// R5 = PHASE-ABLATION DIAGNOSTIC. R4 falsified the RMW-fetch theory (NT run:
// FETCH=10.8MB = input-only, so L2 merges partial-line stores fine; NT itself
// was 2.4x slower -> reverted). T_kernel ~= 18us (R3) but the phase split
// {zero+scan+atomics} vs {write-out} is unknown and my per-block model says
// ~2.5us -- a 7x gap I can't localize from fill-dominated top-5 counters.
//
// This round: launch the exact R0-best kernel ONCE (produces the verified
// output), then 6x an ABLATED variant: identical zero/scan/atomic phases,
// but write-out's global stores are replaced by the same LDS gathers reduced
// into a register + one 4B store/thread into the 256MiB workspace (keeps all
// phases live vs DCE; `out` untouched -> bit-identical result; ws is ours to
// scribble). dur = 80.6 + 6*T_nowrite.
//   dur ~100-117 -> write-out dominates -> full-line-store restructure next
//   dur ~160-190 -> scan/atomics dominate -> QW=4 (11 tiles, halved scan)
//   dur ~130-150 -> both; attack write first.
//
// Gather-style privatization. Output (S=22223, Q=300) tiled as (level-aligned
// row tiles) x (8-wide q' groups). One block per tile: zero LDS -> scan the
// q-group's samples for the tile's level, filter by tile rows, LDS-atomic the
// 4 bilinear corners -> coalesced write-out. Output written exactly once.
//
// Occupancy: LDS = 8*1280*4 = 40960 B exactly => 4 blocks/CU, 32 waves/CU.
// Grid 38*21 = 798 <= 1024 resident slots.
//
// Static shapes: N=1, L=6, Q=300, H=8, Lv=4, P=4; TOT=230400 samples.
// spatial: (100,167),(50,84),(25,42),(13,21); lsi = 0,16700,20900,21950.

constexpr int NQ   = 300;
constexpr int QW   = 8;                  // q'-group width
constexpr int NG   = 38;                 // ceil(300/8)
constexpr int NTILES = 21;               // 15 (L0,R=7) + 4 (L1,R=15) + 1 (L2) + 1 (L3)
constexpr int MAXC = 1280;               // cells cap: L0 7*167=1169, L1 15*84=1260, L2 1050
constexpr int BLK  = 512;

// Shared phase macro-free body: templated on ABLATE to keep the two variants
// byte-comparable through the atomic phase.
template <bool ABLATE>
__global__ __launch_bounds__(BLK, 8)
void msda_tiled_t(const float4* __restrict__ loc4,
                  const float4* __restrict__ aw4,
                  float*        __restrict__ dst) {  // out (ABLATE=0) or ws (ABLATE=1)
    __shared__ float sm[QW * MAXC];               // 40,960 B, ql-major

    const int b  = blockIdx.x;
    const int g  = b / NTILES;                    // q'-group 0..37
    const int tb = b % NTILES;                    // s-tile id

    int lv, r0t, nr;
    if (tb < 15)      { lv = 0; r0t = 7  * tb;        nr = min(7,  100 - r0t); }
    else if (tb < 19) { lv = 1; r0t = 15 * (tb - 15); nr = min(15, 50  - r0t); }
    else if (tb < 20) { lv = 2; r0t = 0;              nr = 25; }
    else              { lv = 3; r0t = 0;              nr = 13; }

    const int Wlv_[4] = {167, 84, 42, 21};
    const int Hlv_[4] = {100, 50, 25, 13};
    const int lsi_[4] = {0, 16700, 20900, 21950};
    const int W    = Wlv_[lv];
    const int base = lsi_[lv];
    const int g0   = g * QW;
    const int qw   = min(QW, NQ - g0);            // 8, or 4 for the last group
    const int cells = nr * W;
    const int tid  = threadIdx.x;

    // zero the used LDS rows (qw full rows), float4 stores
    {
        const int nz = qw * (MAXC / 4);
        float4* sm4 = (float4*)sm;
        for (int i = tid; i < nz; i += BLK) sm4[i] = make_float4(0.f, 0.f, 0.f, 0.f);
    }
    __syncthreads();

    // scan: one thread per mi; mi in [0, 48*qw). m = 48*g0 + mi.
    // Sample flat index t = 16*m + 4*lv + p; the 4 p-samples are contiguous.
    const int nm  = 48 * qw;                      // 384 (192 last group)
    const int rlo = r0t, rhi = r0t + nr;
    const float fW = (float)W, fH = (float)Hlv_[lv];

    if (tid < nm) {
        const int mi = tid;
        const int m  = 48 * g0 + mi;
        const int ql = mi / 48;                   // local q' index in [0, qw)
        const int l  = m / 2400;
        const int rem = m - l * 2400;
        const int h  = rem / 300;
        const int q  = rem - h * 300;
        const int t  = (((l * 300 + q) * 8 + h) * 4 + lv) * 4;   // p=0 base

        const float4 xy01 = loc4[(t >> 1) + 0];   // (x0,y0,x1,y1)
        const float4 xy23 = loc4[(t >> 1) + 1];   // (x2,y2,x3,y3)
        const float4 w4   = aw4[t >> 2];

        float* smq = &sm[ql * MAXC];

        #pragma unroll
        for (int p = 0; p < 4; ++p) {
            const float x = (p == 0) ? xy01.x : (p == 1) ? xy01.z : (p == 2) ? xy23.x : xy23.z;
            const float y = (p == 0) ? xy01.y : (p == 1) ? xy01.w : (p == 2) ? xy23.y : xy23.w;
            const float w = (p == 0) ? w4.x   : (p == 1) ? w4.y   : (p == 2) ? w4.z   : w4.w;

            const float cf  = x * fW;
            const float rf  = y * fH;
            const float cfl = floorf(cf), rfl = floorf(rf);
            const float fc  = cf - cfl, fr = rf - rfl;
            const int c0 = (int)cfl, rr = (int)rfl;
            const int c1 = c0 + 1, r1 = rr + 1;

            const bool cv0 = (unsigned)c0 < (unsigned)W;   // 0 <= c0 < W
            const bool cv1 = (unsigned)c1 < (unsigned)W;
            const bool rv0 = (rr >= rlo) & (rr < rhi);     // in-tile (implies 0<=r<H)
            const bool rv1 = (r1 >= rlo) & (r1 < rhi);

            const float omfc = 1.0f - fc, omfr = 1.0f - fr;
            if (rv0) {
                const int ro = (rr - rlo) * W;
                if (cv0) atomicAdd(&smq[ro + c0], w * omfc * omfr);
                if (cv1) atomicAdd(&smq[ro + c1], w * fc   * omfr);
            }
            if (rv1) {
                const int ro = (r1 - rlo) * W;
                if (cv0) atomicAdd(&smq[ro + c0], w * omfc * fr);
                if (cv1) atomicAdd(&smq[ro + c1], w * fc   * fr);
            }
        }
    }
    __syncthreads();

    // write-out (full) or register-reduce (ablated): same LDS gather pattern.
    const int s0  = base + r0t * W;
    const int nq4 = qw >> 2;                      // 2 (or 1 last group)
    if constexpr (!ABLATE) {
        for (int i = tid; i < cells * nq4; i += BLK) {
            const int cell = i / nq4;
            const int v    = i - cell * nq4;
            float4 val;
            val.x = sm[(v * 4 + 0) * MAXC + cell];
            val.y = sm[(v * 4 + 1) * MAXC + cell];
            val.z = sm[(v * 4 + 2) * MAXC + cell];
            val.w = sm[(v * 4 + 3) * MAXC + cell];
            *(float4*)&dst[(s0 + cell) * NQ + g0 + v * 4] = val;
        }
    } else {
        // keep atomics + gathers live, drop the global-store traffic:
        // reduce gathered values into one register, one 4B store to ws.
        float acc = 0.f;
        for (int i = tid; i < cells * nq4; i += BLK) {
            const int cell = i / nq4;
            const int v    = i - cell * nq4;
            acc += sm[(v * 4 + 0) * MAXC + cell] + sm[(v * 4 + 1) * MAXC + cell]
                 + sm[(v * 4 + 2) * MAXC + cell] + sm[(v * 4 + 3) * MAXC + cell];
        }
        dst[b * BLK + tid] = acc;                 // 1.6MB total, coalesced, negligible
    }
}

extern "C" void kernel_launch(void* const* d_in, const int* in_sizes, int n_in,
                              void* d_out, int out_size, void* d_ws, size_t ws_size,
                              hipStream_t stream) {
    const float4* loc4 = (const float4*)d_in[0];  // sampling_locations (fp32), 16B-aligned
    const float4* aw4  = (const float4*)d_in[1];  // attention_weights  (fp32), 16B-aligned
    float* out = (float*)d_out;
    float* ws  = (float*)d_ws;

    // 1x full kernel -> correct output (exact R0 best, 80.6us baseline).
    msda_tiled_t<false><<<NG * NTILES, BLK, 0, stream>>>(loc4, aw4, out);
    // 6x ablated (no global write-out; scribbles ws only): dur = 80.6 + 6*T_nw.
    for (int rep = 0; rep < 6; ++rep)
        msda_tiled_t<true><<<NG * NTILES, BLK, 0, stream>>>(loc4, aw4, ws);
}

// Round 6
// 86.195 us; speedup vs baseline: 1.9532x; 1.9532x over previous
//
#include <hip/hip_runtime.h>

// MSDeformAttn sampling-weight scatter (RankDetr), bug-compatible with the
// reference's axis-mislabeled reshape: output column q' = m/48, m=(l*8+h)*300+q.
//
// R6: TILE-MERGE. R5's ablation split T_kernel(18.1us): scan+zero+LDS = 14.6,
// write-out = 3.5 (cross-checked vs R4's NT run: 43us total - ~28us NT writes
// = ~15us scan). Scan cost scales with block count: per-block scan work is
// fixed (384 thr x 3 line-hostile loads: loc4 stride 1024B, aw4 512B per q ->
// each lane pulls its own 128B line, 98KB lines/block for 18.4KB used; R4
// FETCH=10.8MB = 4x input confirms). So: MAXC 1280->2048 (64KB static LDS,
// the per-WG limit), tiles 21->14 (L0: 9x12rows, L1: 3x17rows, L2, L3),
// grid 798->532 blocks. Occupancy 4->2 blocks/CU (16 waves/CU) but 1.5x less
// redundant scan + all-but-20 blocks co-resident. Also: zero only `cells`
// columns per row (not full MAXC), and issue scan loads BEFORE the zero loop
// (cold ~900cy miss drains under LDS zeroing).
// Predicted: scan 14.6 -> ~10, dur 80.6 -> 74-77. If >=79, lever is dead ->
// compaction pre-pass next.
//
// Gather-style privatization. Output (S=22223, Q=300) tiled as (level-aligned
// row tiles) x (8-wide q' groups). One block per tile: zero LDS -> scan the
// q-group's samples for the tile's level, filter by tile rows, LDS-atomic the
// 4 bilinear corners -> coalesced float4 write-out. Output written exactly
// once, no memset needed.
//
// Static shapes: N=1, L=6, Q=300, H=8, Lv=4, P=4; TOT=230400 samples.
// spatial: (100,167),(50,84),(25,42),(13,21); lsi = 0,16700,20900,21950.

constexpr int NQ   = 300;
constexpr int QW   = 8;                  // q'-group width
constexpr int NG   = 38;                 // ceil(300/8)
constexpr int NTILES = 14;               // 9 (L0,R=12) + 3 (L1,R=17) + 1 (L2) + 1 (L3)
constexpr int MAXC = 2048;               // cells cap: L0 12*167=2004, L1 17*84=1428, L2 1050
constexpr int BLK  = 512;

__global__ __launch_bounds__(BLK, 4)     // 2 blocks/CU (64KB LDS), 16 waves/CU
void msda_tiled(const float4* __restrict__ loc4,  // sampling_locations as float4 (2 samples each)
                const float4* __restrict__ aw4,   // attention_weights  (4 samples each)
                float*        __restrict__ out) { // (S, NQ)
    __shared__ float sm[QW * MAXC];               // 65,536 B exactly (static LDS limit)

    const int b  = blockIdx.x;
    const int g  = b / NTILES;                    // q'-group 0..37
    const int tb = b % NTILES;                    // s-tile id

    int lv, r0t, nr;
    if (tb < 9)       { lv = 0; r0t = 12 * tb;        nr = min(12, 100 - r0t); }
    else if (tb < 12) { lv = 1; r0t = 17 * (tb - 9);  nr = min(17, 50  - r0t); }
    else if (tb < 13) { lv = 2; r0t = 0;              nr = 25; }
    else              { lv = 3; r0t = 0;              nr = 13; }

    const int Wlv_[4] = {167, 84, 42, 21};
    const int Hlv_[4] = {100, 50, 25, 13};
    const int lsi_[4] = {0, 16700, 20900, 21950};
    const int W    = Wlv_[lv];
    const int base = lsi_[lv];
    const int g0   = g * QW;
    const int qw   = min(QW, NQ - g0);            // 8, or 4 for the last group
    const int cells = nr * W;
    const int tid  = threadIdx.x;

    // ---- scan loads FIRST: issue the 3 vector loads, then zero LDS while
    // the cold-HBM misses (caches flushed by the harness poison fill) drain.
    const int nm  = 48 * qw;                      // 384 (192 last group)
    float4 xy01, xy23, w4;
    int ql = 0;
    if (tid < nm) {
        const int mi = tid;
        const int m  = 48 * g0 + mi;
        ql = mi / 48;                             // local q' index in [0, qw)
        const int l  = m / 2400;
        const int rem = m - l * 2400;
        const int h  = rem / 300;
        const int q  = rem - h * 300;
        const int t  = (((l * 300 + q) * 8 + h) * 4 + lv) * 4;   // p=0 base
        xy01 = loc4[(t >> 1) + 0];                // (x0,y0,x1,y1)
        xy23 = loc4[(t >> 1) + 1];                // (x2,y2,x3,y3)
        w4   = aw4[t >> 2];
    }

    // zero only the used columns of the qw used rows (float4 granularity).
    {
        const int c4 = (cells + 3) >> 2;          // float4s per row actually used
        float4* sm4 = (float4*)sm;
        const float4 z4 = make_float4(0.f, 0.f, 0.f, 0.f);
        for (int i = tid; i < qw * c4; i += BLK) {
            const int row = i / c4;
            const int col = i - row * c4;
            sm4[row * (MAXC / 4) + col] = z4;
        }
    }
    __syncthreads();

    // scan compute: one thread per mi; its 4 p-samples were loaded above.
    const int rlo = r0t, rhi = r0t + nr;
    const float fW = (float)W, fH = (float)Hlv_[lv];

    if (tid < nm) {
        float* smq = &sm[ql * MAXC];

        #pragma unroll
        for (int p = 0; p < 4; ++p) {
            const float x = (p == 0) ? xy01.x : (p == 1) ? xy01.z : (p == 2) ? xy23.x : xy23.z;
            const float y = (p == 0) ? xy01.y : (p == 1) ? xy01.w : (p == 2) ? xy23.y : xy23.w;
            const float w = (p == 0) ? w4.x   : (p == 1) ? w4.y   : (p == 2) ? w4.z   : w4.w;

            const float cf  = x * fW;
            const float rf  = y * fH;
            const float cfl = floorf(cf), rfl = floorf(rf);
            const float fc  = cf - cfl, fr = rf - rfl;
            const int c0 = (int)cfl, rr = (int)rfl;
            const int c1 = c0 + 1, r1 = rr + 1;

            const bool cv0 = (unsigned)c0 < (unsigned)W;   // 0 <= c0 < W
            const bool cv1 = (unsigned)c1 < (unsigned)W;
            const bool rv0 = (rr >= rlo) & (rr < rhi);     // in-tile (implies 0<=r<H)
            const bool rv1 = (r1 >= rlo) & (r1 < rhi);

            const float omfc = 1.0f - fc, omfr = 1.0f - fr;
            if (rv0) {
                const int ro = (rr - rlo) * W;
                if (cv0) atomicAdd(&smq[ro + c0], w * omfc * omfr);
                if (cv1) atomicAdd(&smq[ro + c1], w * fc   * omfr);
            }
            if (rv1) {
                const int ro = (r1 - rlo) * W;
                if (cv0) atomicAdd(&smq[ro + c0], w * omfc * fr);
                if (cv1) atomicAdd(&smq[ro + c1], w * fc   * fr);
            }
        }
    }
    __syncthreads();

    // write-out: s in [base + r0t*W, +cells), q' in [g0, g0+qw).
    // One float4 global store per (cell, v); LDS gathers are 2 lanes/bank
    // (MAXC % 32 == 0 -> bank = cell % 32; free per m136). L2 merges the 32B
    // partial-line stores (R4 falsified the RMW theory; NT was 2.4x worse).
    const int s0  = base + r0t * W;
    const int nq4 = qw >> 2;                      // 2 (or 1 last group)
    for (int i = tid; i < cells * nq4; i += BLK) {
        const int cell = i / nq4;
        const int v    = i - cell * nq4;
        float4 val;
        val.x = sm[(v * 4 + 0) * MAXC + cell];
        val.y = sm[(v * 4 + 1) * MAXC + cell];
        val.z = sm[(v * 4 + 2) * MAXC + cell];
        val.w = sm[(v * 4 + 3) * MAXC + cell];
        *(float4*)&out[(s0 + cell) * NQ + g0 + v * 4] = val;
    }
}

extern "C" void kernel_launch(void* const* d_in, const int* in_sizes, int n_in,
                              void* d_out, int out_size, void* d_ws, size_t ws_size,
                              hipStream_t stream) {
    const float4* loc4 = (const float4*)d_in[0];  // sampling_locations (fp32), 16B-aligned
    const float4* aw4  = (const float4*)d_in[1];  // attention_weights  (fp32), 16B-aligned
    float* out = (float*)d_out;

    msda_tiled<<<NG * NTILES, BLK, 0, stream>>>(loc4, aw4, out);
}

// Round 8
// 82.915 us; speedup vs baseline: 2.0305x; 1.0396x over previous
//
#include <hip/hip_runtime.h>

// MSDeformAttn sampling-weight scatter (RankDetr), bug-compatible with the
// reference's axis-mislabeled reshape: output column q' = m/48, m=(l*8+h)*300+q.
//
// R8: COMPACTION PRE-PASS (permutation-FIXED) + exact-R0 tile kernel.
// R7 failed correctness (absmax 0.699): input memory layout is (N,L,Q,H,Lv,P)
// -> memory sample row s=(l*300+q)*8+h, but output order is m=(l*8+h)*300+q.
// R7's compaction keyed ws by s while the tile kernel read by m, dropping the
// (l,q,h)->(l,h,q) permutation. Fixed: compaction thread owns output-order
// (m,lv), computes s from m (R0's div-chain, now paid once in the 225-block
// pre-pass), reads loc4[8s+2lv],[+1], aw4[4s+lv], writes ws[lv][m] = 48B
// contiguous. Kernel 2 unchanged (= R0 + contiguous scan loads: a wave reads
// 3KB sequential vs ~128 scattered 128B lines before).
// Theory under test (R5 ablation: scan/zero/LDS=14.6us of T_kernel=18.1;
// R6 showed occupancy must stay at 4 blocks/CU): the scan's line-hostile
// gather (98KB lines/block, 78MB total; R4 FETCH=10.8MB=4x input) is the
// dominant cost. Predicted: scan 14.6 -> 6-9us, pre-pass +1-2us, write 3.5
// unchanged -> dur 73-78. If >=79: scattered loads weren't the cost.
//
// Gather-style privatization. Output (S=22223, Q=300) tiled as (level-aligned
// row tiles) x (8-wide q' groups). One block per tile: zero LDS -> scan the
// q-group's samples for the tile's level, filter by tile rows, LDS-atomic the
// 4 bilinear corners -> coalesced float4 write-out. Output written exactly
// once, no memset needed.
//
// Occupancy: LDS = 8*1280*4 = 40960 B exactly => 4 blocks/CU, 32 waves/CU.
// Grid 38*21 = 798 <= 1024 resident slots.
//
// Static shapes: N=1, L=6, Q=300, H=8, Lv=4, P=4; M=14400, TOT=230400.
// spatial: (100,167),(50,84),(25,42),(13,21); lsi = 0,16700,20900,21950.

constexpr int NQ   = 300;
constexpr int QW   = 8;                  // q'-group width
constexpr int NG   = 38;                 // ceil(300/8)
constexpr int NTILES = 21;               // 15 (L0,R=7) + 4 (L1,R=15) + 1 (L2) + 1 (L3)
constexpr int MAXC = 1280;               // cells cap: L0 7*167=1169, L1 15*84=1260, L2 1050
constexpr int BLK  = 512;
constexpr int MTOT = 14400;              // N*L*H*Q

// ---------------- kernel 1: input compaction to (lv, m_out) layout ------------
// ws4[(lv*MTOT + m)*3 + {0,1,2}] = {(x0,y0,x1,y1), (x2,y2,x3,y3), (w0,w1,w2,w3)}
// where m is OUTPUT-order: m = (l*8+h)*300+q. Memory sample row s=(l*300+q)*8+h;
// for (m,lv): loc4 at 8s+2lv, 8s+2lv+1; aw4 at 4s+lv (cf. R0's
// t=(((l*300+q)*8+h)*4+lv)*4, loc4=t>>1, aw4=t>>2). Lanes 4k..4k+3 (lv 0..3,
// same m) consume one full 128B loc line; writes are contiguous 48B chunks.
__global__ __launch_bounds__(256, 8)
void msda_compact(const float4* __restrict__ loc4,
                  const float4* __restrict__ aw4,
                  float4*       __restrict__ ws4) {
    const int tid = blockIdx.x * 256 + threadIdx.x;   // tid = 4*m + lv
    if (tid >= MTOT * 4) return;
    const int lv = tid & 3;
    const int m  = tid >> 2;                          // output-order m
    const int l  = m / 2400;
    const int rem = m - l * 2400;
    const int h  = rem / 300;
    const int q  = rem - h * 300;
    const int s  = (l * 300 + q) * 8 + h;             // memory-order sample row
    const float4 a = loc4[8 * s + 2 * lv];            // (x0,y0,x1,y1)
    const float4 b = loc4[8 * s + 2 * lv + 1];        // (x2,y2,x3,y3)
    const float4 c = aw4[4 * s + lv];                 // (w0,w1,w2,w3)
    float4* dst = &ws4[((size_t)(lv * MTOT + m)) * 3];
    dst[0] = a;
    dst[1] = b;
    dst[2] = c;
}

// ---------------- kernel 2: exact R0 tile kernel, contiguous scan loads -------
__global__ __launch_bounds__(BLK, 8)
void msda_tiled(const float4* __restrict__ ws4,   // compacted (lv, m_out) input
                float*        __restrict__ out) { // (S, NQ)
    __shared__ float sm[QW * MAXC];               // 40,960 B, ql-major

    const int b  = blockIdx.x;
    const int g  = b / NTILES;                    // q'-group 0..37
    const int tb = b % NTILES;                    // s-tile id

    int lv, r0t, nr;
    if (tb < 15)      { lv = 0; r0t = 7  * tb;        nr = min(7,  100 - r0t); }
    else if (tb < 19) { lv = 1; r0t = 15 * (tb - 15); nr = min(15, 50  - r0t); }
    else if (tb < 20) { lv = 2; r0t = 0;              nr = 25; }
    else              { lv = 3; r0t = 0;              nr = 13; }

    const int Wlv_[4] = {167, 84, 42, 21};
    const int Hlv_[4] = {100, 50, 25, 13};
    const int lsi_[4] = {0, 16700, 20900, 21950};
    const int W    = Wlv_[lv];
    const int base = lsi_[lv];
    const int g0   = g * QW;
    const int qw   = min(QW, NQ - g0);            // 8, or 4 for the last group
    const int cells = nr * W;
    const int tid  = threadIdx.x;

    // scan loads FIRST (contiguous: thread mi reads 48B at ws[lv][48*g0+mi];
    // a wave reads 3KB sequential). Miss latency drains under the LDS zero.
    const int nm  = 48 * qw;                      // 384 (192 last group)
    float4 xy01, xy23, w4;
    int ql = 0;
    if (tid < nm) {
        const int mi = tid;
        ql = mi / 48;                             // local q' index in [0, qw)
        const float4* src = &ws4[((size_t)(lv * MTOT + 48 * g0 + mi)) * 3];
        xy01 = src[0];                            // (x0,y0,x1,y1)
        xy23 = src[1];                            // (x2,y2,x3,y3)
        w4   = src[2];                            // (w0,w1,w2,w3)
    }

    // zero the used LDS rows (qw full rows), float4 stores
    {
        const int nz = qw * (MAXC / 4);
        float4* sm4 = (float4*)sm;
        for (int i = tid; i < nz; i += BLK) sm4[i] = make_float4(0.f, 0.f, 0.f, 0.f);
    }
    __syncthreads();

    // scan compute: one thread per mi; its 4 p-samples were loaded above.
    const int rlo = r0t, rhi = r0t + nr;
    const float fW = (float)W, fH = (float)Hlv_[lv];

    if (tid < nm) {
        float* smq = &sm[ql * MAXC];

        #pragma unroll
        for (int p = 0; p < 4; ++p) {
            const float x = (p == 0) ? xy01.x : (p == 1) ? xy01.z : (p == 2) ? xy23.x : xy23.z;
            const float y = (p == 0) ? xy01.y : (p == 1) ? xy01.w : (p == 2) ? xy23.y : xy23.w;
            const float w = (p == 0) ? w4.x   : (p == 1) ? w4.y   : (p == 2) ? w4.z   : w4.w;

            const float cf  = x * fW;
            const float rf  = y * fH;
            const float cfl = floorf(cf), rfl = floorf(rf);
            const float fc  = cf - cfl, fr = rf - rfl;
            const int c0 = (int)cfl, rr = (int)rfl;
            const int c1 = c0 + 1, r1 = rr + 1;

            const bool cv0 = (unsigned)c0 < (unsigned)W;   // 0 <= c0 < W
            const bool cv1 = (unsigned)c1 < (unsigned)W;
            const bool rv0 = (rr >= rlo) & (rr < rhi);     // in-tile (implies 0<=r<H)
            const bool rv1 = (r1 >= rlo) & (r1 < rhi);

            const float omfc = 1.0f - fc, omfr = 1.0f - fr;
            if (rv0) {
                const int ro = (rr - rlo) * W;
                if (cv0) atomicAdd(&smq[ro + c0], w * omfc * omfr);
                if (cv1) atomicAdd(&smq[ro + c1], w * fc   * omfr);
            }
            if (rv1) {
                const int ro = (r1 - rlo) * W;
                if (cv0) atomicAdd(&smq[ro + c0], w * omfc * fr);
                if (cv1) atomicAdd(&smq[ro + c1], w * fc   * fr);
            }
        }
    }
    __syncthreads();

    // write-out: s in [base + r0t*W, +cells), q' in [g0, g0+qw).
    // One float4 global store per (cell, v); LDS gathers are 2 lanes/bank
    // (free per m136). L2 merges the 32B partial-line stores (R4 falsified
    // the RMW theory; NT stores were 2.4x worse).
    const int s0  = base + r0t * W;
    const int nq4 = qw >> 2;                      // 2 (or 1 last group)
    for (int i = tid; i < cells * nq4; i += BLK) {
        const int cell = i / nq4;
        const int v    = i - cell * nq4;
        float4 val;
        val.x = sm[(v * 4 + 0) * MAXC + cell];
        val.y = sm[(v * 4 + 1) * MAXC + cell];
        val.z = sm[(v * 4 + 2) * MAXC + cell];
        val.w = sm[(v * 4 + 3) * MAXC + cell];
        *(float4*)&out[(s0 + cell) * NQ + g0 + v * 4] = val;
    }
}

extern "C" void kernel_launch(void* const* d_in, const int* in_sizes, int n_in,
                              void* d_out, int out_size, void* d_ws, size_t ws_size,
                              hipStream_t stream) {
    const float4* loc4 = (const float4*)d_in[0];  // sampling_locations (fp32), 16B-aligned
    const float4* aw4  = (const float4*)d_in[1];  // attention_weights  (fp32), 16B-aligned
    float* out  = (float*)d_out;
    float4* ws4 = (float4*)d_ws;                  // 2.76MB of the 256MB workspace

    // 1) compact input to (lv, m_out) layout: 57600 threads, 225 blocks.
    msda_compact<<<(MTOT * 4) / 256, 256, 0, stream>>>(loc4, aw4, ws4);
    // 2) tile kernel (exact R0 structure), scan loads now contiguous.
    msda_tiled<<<NG * NTILES, BLK, 0, stream>>>(ws4, out);
}